// Round 4
// baseline (356.246 us; speedup 1.0000x reference)
//
#include <hip/hip_runtime.h>

#define B_DIM   512
#define IN_DIM  65536
#define OUT_DIM 16384
#define K_DIM   32

static __device__ __forceinline__ unsigned f2bf(float f) {
    unsigned u = __builtin_bit_cast(unsigned, f);
    return (u + 0x7FFFu + ((u >> 16) & 1u)) >> 16;   // round-to-nearest-even
}

// ---------------------------------------------------------------------------
// Kernel 1: pack (idx:int32, w:fp32) -> u32 = bf16(w)<<16 | u16(idx).
// IN_DIM = 65536 so idx fits u16 exactly. 512K elements, vec4 -> ~3 us.
// ---------------------------------------------------------------------------
__global__ __launch_bounds__(256) void pack_k(const int* __restrict__ idxp,
                                              const float* __restrict__ wp,
                                              unsigned* __restrict__ packed) {
    const int i = blockIdx.x * 256 + threadIdx.x;          // vec4 index
    const int4   iv = ((const int4*)idxp)[i];
    const float4 wv = ((const float4*)wp)[i];
    uint4 p;
    p.x = ((unsigned)iv.x & 0xFFFFu) | (f2bf(wv.x) << 16);
    p.y = ((unsigned)iv.y & 0xFFFFu) | (f2bf(wv.y) << 16);
    p.z = ((unsigned)iv.z & 0xFFFFu) | (f2bf(wv.z) << 16);
    p.w = ((unsigned)iv.w & 0xFFFFu) | (f2bf(wv.w) << 16);
    ((uint4*)packed)[i] = p;
}

// ---------------------------------------------------------------------------
// Kernel 2: fused main. One block per b (512 blocks, 1024 threads).
// Stage x[b,:] into LDS as bf16 (128 KiB), then each thread computes 16
// outputs: 8x uint4 packed-metadata loads (all independent -> deep MLP,
// L2/L3-resident stream), 32 random LDS u16 gathers + fp32 FMA per output.
// Out writes: lanes span consecutive o -> fully coalesced 64 KiB/block row.
// ---------------------------------------------------------------------------
__global__ __launch_bounds__(1024) void fused_k(const float* __restrict__ x,
                                                const unsigned* __restrict__ packed,
                                                const float* __restrict__ biasp,
                                                float* __restrict__ out) {
    __shared__ unsigned short xs[IN_DIM];    // 128 KiB bf16 row
    const int b = blockIdx.x;
    const int t = threadIdx.x;

    // ---- stage: x[b,:] fp32 -> bf16 LDS, 16 float4 loads/thread ----
    const float4* xr = (const float4*)(x + (size_t)b * IN_DIM);
    unsigned* xs32 = (unsigned*)xs;
    #pragma unroll
    for (int j = 0; j < 16; ++j) {
        const int e = j * 1024 + t;          // float4 index within row
        float4 v = xr[e];
        uint2 pkt;
        pkt.x = f2bf(v.x) | (f2bf(v.y) << 16);
        pkt.y = f2bf(v.z) | (f2bf(v.w) << 16);
        *(uint2*)(xs32 + 2 * e) = pkt;       // ds_write_b64, conflict-free
    }
    __syncthreads();

    // ---- compute: 16 outputs per thread, o = j*1024 + t (coalesced) ----
    #pragma unroll 2
    for (int j = 0; j < 16; ++j) {
        const int o = j * 1024 + t;
        const uint4* pr = (const uint4*)(packed + (size_t)o * K_DIM);
        uint4 q[8];
        #pragma unroll
        for (int c = 0; c < 8; ++c) q[c] = pr[c];   // 8 independent 16B loads

        float acc = 0.f;
        #pragma unroll
        for (int c = 0; c < 8; ++c) {
            const unsigned u0 = q[c].x, u1 = q[c].y, u2 = q[c].z, u3 = q[c].w;
            acc = fmaf(__uint_as_float(u0 & 0xFFFF0000u),
                       __uint_as_float(((unsigned)xs[u0 & 0xFFFFu]) << 16), acc);
            acc = fmaf(__uint_as_float(u1 & 0xFFFF0000u),
                       __uint_as_float(((unsigned)xs[u1 & 0xFFFFu]) << 16), acc);
            acc = fmaf(__uint_as_float(u2 & 0xFFFF0000u),
                       __uint_as_float(((unsigned)xs[u2 & 0xFFFFu]) << 16), acc);
            acc = fmaf(__uint_as_float(u3 & 0xFFFF0000u),
                       __uint_as_float(((unsigned)xs[u3 & 0xFFFFu]) << 16), acc);
        }
        out[(size_t)b * OUT_DIM + o] = acc + biasp[o];
    }
}

// ---------------------------------------------------------------------------
// Fallback (workspace too small): direct gather, correct but slow.
// ---------------------------------------------------------------------------
__global__ void sparse_fallback(const float* __restrict__ x,
                                const int*   __restrict__ idxp,
                                const float* __restrict__ wp,
                                const float* __restrict__ biasp,
                                float*       __restrict__ out) {
    const int i = blockIdx.x * blockDim.x + threadIdx.x;
    if (i >= B_DIM * OUT_DIM) return;
    const int b = i / OUT_DIM;
    const int o = i % OUT_DIM;
    float a = biasp[o];
    for (int k = 0; k < K_DIM; ++k) {
        const int idx = idxp[o * K_DIM + k];
        a = fmaf(wp[o * K_DIM + k], x[(size_t)b * IN_DIM + idx], a);
    }
    out[i] = a;
}

extern "C" void kernel_launch(void* const* d_in, const int* in_sizes, int n_in,
                              void* d_out, int out_size, void* d_ws, size_t ws_size,
                              hipStream_t stream) {
    const float* x       = (const float*)d_in[0];
    const int*   indices = (const int*)  d_in[1];
    const float* weight  = (const float*)d_in[2];
    const float* bias    = (const float*)d_in[3];
    float*       out     = (float*)d_out;

    const size_t need = (size_t)OUT_DIM * K_DIM * sizeof(unsigned);  // 2 MiB
    if (ws_size >= need) {
        unsigned* packed = (unsigned*)d_ws;
        pack_k<<<(OUT_DIM * K_DIM / 4) / 256, 256, 0, stream>>>(indices, weight, packed);
        fused_k<<<B_DIM, 1024, 0, stream>>>(x, packed, bias, out);
    } else {
        const int n = B_DIM * OUT_DIM;
        sparse_fallback<<<(n + 255) / 256, 256, 0, stream>>>(x, indices, weight, bias, out);
    }
}